// Round 8
// baseline (216.521 us; speedup 1.0000x reference)
//
#include <hip/hip_runtime.h>
#include <hip/hip_bf16.h>

typedef __hip_bfloat16 bf16;
typedef unsigned short u16;
typedef unsigned int u32;
typedef float f32x4 __attribute__((ext_vector_type(4)));
typedef float f32x16 __attribute__((ext_vector_type(16)));
typedef __bf16 bf16x8 __attribute__((ext_vector_type(8)));
typedef u16 u16x8 __attribute__((ext_vector_type(8)));

#define DMODEL 1024
#define NH 16
#define HD 64
#define QKV_LD 3072

typedef __attribute__((address_space(1))) const void* as1_cvp;
typedef __attribute__((address_space(3))) void* as3_vp;

__device__ __forceinline__ void gload_lds16(const void* g, void* l) {
  __builtin_amdgcn_global_load_lds((as1_cvp)g, (as3_vp)l, 16, 0, 0);
}

__device__ __forceinline__ f32x4 mfma16(bf16x8 a, bf16x8 b, f32x4 c) {
  return __builtin_amdgcn_mfma_f32_16x16x32_bf16(a, b, c, 0, 0, 0);
}
__device__ __forceinline__ f32x16 mfma32(bf16x8 a, bf16x8 b, f32x16 c) {
  return __builtin_amdgcn_mfma_f32_32x32x16_bf16(a, b, c, 0, 0, 0);
}

__device__ __forceinline__ u16 f2b(float f) {
  union { bf16 b; u16 s; } u; u.b = __float2bfloat16(f); return u.s;
}
__device__ __forceinline__ u32 pkbf(float a, float b) {
  union { __hip_bfloat162 h; u32 u; } cv;
  cv.h = __float22bfloat162_rn(make_float2(a, b));
  return cv.u;
}

// ---------------- fp32 -> bf16 conversion, 4 elems/thread ----------------
__global__ __launch_bounds__(256) void cvt_kernel(const float* __restrict__ src,
                                                  bf16* __restrict__ dst, int n) {
  int i = (blockIdx.x * 256 + threadIdx.x) * 4;
  if (i >= n) return;
  float4 v = *(const float4*)(src + i);
  union { ushort4 u; bf16 h[4]; } o;
  o.h[0] = __float2bfloat16(v.x);
  o.h[1] = __float2bfloat16(v.y);
  o.h[2] = __float2bfloat16(v.z);
  o.h[3] = __float2bfloat16(v.w);
  *(ushort4*)(dst + i) = o.u;
}

// ---------------- RoPE on Q and K regions of QKV, in place ----------------
__global__ __launch_bounds__(256) void rope_kernel(bf16* __restrict__ qkv) {
  int idx = blockIdx.x * 256 + threadIdx.x;
  int p = idx & 511;
  int s = (idx >> 9) & 4095;
  int region = idx >> 21;
  int i = p & 31;
  int h = p >> 5;
  long base = (long)s * QKV_LD + region * DMODEL + h * HD + 2 * i;
  float x1 = __bfloat162float(qkv[base]);
  float x2 = __bfloat162float(qkv[base + 1]);
  float invf = powf(10000.0f, -(float)(2 * i) / 64.0f);
  float ang = (float)s * invf;
  float sn, cs;
  sincosf(ang, &sn, &cs);
  float scale = (region == 0) ? 0.125f : 1.0f;
  float r1 = (x1 * cs - x2 * sn) * scale;
  float r2 = (x1 * sn + x2 * cs) * scale;
  qkv[base]     = __float2bfloat16(r1);
  qkv[base + 1] = __float2bfloat16(r2);
}

// ---------------- NT GEMM (unchanged) ----------------
template <int OUT_BF16>
__global__ __launch_bounds__(256) void gemm_bt(const bf16* __restrict__ A,
                                               const bf16* __restrict__ B,
                                               void* __restrict__ Cout,
                                               const float* __restrict__ bias,
                                               int M, int N, int K) {
  __shared__ __align__(16) bf16 As[128 * 32];
  __shared__ __align__(16) bf16 Bs[128 * 32];
  const int tid = threadIdx.x;
  const int lane = tid & 63;
  const int wid = tid >> 6;
  const int brow = blockIdx.y * 128;
  const int bcol = blockIdx.x * 128;
  const int wr = wid >> 1, wc = wid & 1;

  f32x4 acc[4][4] = {};

  const int srow = lane >> 2;
  const int scol = (lane & 3) * 8;
  const bf16* Ag = A + (long)(brow + wid * 32 + srow) * K + scol;
  const bf16* Bg = B + (long)(bcol + wid * 32 + srow) * K + scol;
  bf16* AsW = As + wid * 32 * 32;
  bf16* BsW = Bs + wid * 32 * 32;
  const int kof = (lane >> 4) * 8;
  const int r16 = lane & 15;

  for (int k0 = 0; k0 < K; k0 += 32) {
    __syncthreads();
    gload_lds16(Ag + k0, AsW);
    gload_lds16(Ag + k0 + (long)16 * K, AsW + 16 * 32);
    gload_lds16(Bg + k0, BsW);
    gload_lds16(Bg + k0 + (long)16 * K, BsW + 16 * 32);
    __syncthreads();
    bf16x8 af[4], bfr[4];
#pragma unroll
    for (int m = 0; m < 4; ++m)
      af[m] = *(const bf16x8*)(As + (wr * 64 + m * 16 + r16) * 32 + kof);
#pragma unroll
    for (int n = 0; n < 4; ++n)
      bfr[n] = *(const bf16x8*)(Bs + (wc * 64 + n * 16 + r16) * 32 + kof);
#pragma unroll
    for (int m = 0; m < 4; ++m)
#pragma unroll
      for (int n = 0; n < 4; ++n)
        acc[m][n] = mfma16(af[m], bfr[n], acc[m][n]);
  }

  const int r0 = (lane >> 4) * 4;
#pragma unroll
  for (int m = 0; m < 4; ++m) {
#pragma unroll
    for (int n = 0; n < 4; ++n) {
      int row = brow + wr * 64 + m * 16 + r0;
      int col = bcol + wc * 64 + n * 16 + r16;
#pragma unroll
      for (int r = 0; r < 4; ++r) {
        if (OUT_BF16) {
          ((bf16*)Cout)[(long)(row + r) * N + col] = __float2bfloat16(acc[m][n][r]);
        } else {
          ((float*)Cout)[(long)(row + r) * N + col] = acc[m][n][r] + bias[col];
        }
      }
    }
  }
}

// ---------------- causal flash attention (v7) ----------------
// v6 structure + v4/v5's PROVEN __shfl_xor lane^32 exchanges (raw-asm
// permlane32_swap refuted on HW twice: v3, v6 — likely RAW hazard or
// operand-semantics mismatch; builtin path not yet validated here).
// grid (512): tier = bid>>4 (0..31), head = bid&15. 256 thr = 4 waves.
// Wave group grp=wid>>1 takes qblk 63-tier (heavy) or tier (light), heavy
// group alternating with tier bit4; 64 KB LDS -> 2 blocks/CU, independent
// barrier domains. KVBLK=128 double-buffered, shared by both tiles.
__global__ __launch_bounds__(256, 2) void attn_kernel(const bf16* __restrict__ qkv,
                                                      bf16* __restrict__ ctx) {
  __shared__ __align__(16) bf16 smem[32768];   // 64 KB
  bf16 (*Ks)[128][64] = (bf16(*)[128][64])(smem);           // 2 bufs, [kv][d]
  bf16 (*Vt)[64][128] = (bf16(*)[64][128])(smem + 16384);   // 2 bufs, [d][kv]

  const int tid = threadIdx.x;
  const int lane = tid & 63;
  const int wid = tid >> 6;            // 0..3
  const int hi = lane >> 5;
  const int l31 = lane & 31;
  const int tier = blockIdx.x >> 4;    // 0..31
  const int h = blockIdx.x & 15;
  const int grp = wid >> 1;
  const int wslot = wid & 1;
  const int hv = (tier >> 4) & 1;      // which group is heavy
  const int qblk = (grp == hv) ? (63 - tier) : tier;   // 64-row q tile
  const int q0w = qblk * 64 + wslot * 32;              // wave's q base
  const long kcol = DMODEL + (long)h * HD;
  const long vcol = 2 * DMODEL + (long)h * HD;
  const u16* qkv16 = (const u16*)qkv;

  // Q B-fragments: lane holds Q[q=l31][d = kt*16 + hi*8 .. +8]
  bf16x8 qf[4];
  {
    const bf16* qp = qkv + (long)(q0w + l31) * QKV_LD + h * HD + hi * 8;
#pragma unroll
    for (int kt = 0; kt < 4; ++kt) qf[kt] = *(const bf16x8*)(qp + kt * 16);
  }

  const int kOff = ((lane & 7) ^ (lane >> 3)) * 8;   // pre-swizzled K src col
  const int krow0 = wid * 32 + (lane >> 3);          // K stage row base

  // hoisted swizzled LDS element offsets (sub/cur-invariant parts)
  int kro[4];
#pragma unroll
  for (int kt = 0; kt < 4; ++kt)
    kro[kt] = l31 * 64 + ((((kt << 1) | hi) ^ (l31 & 7)) * 8);
  const int vbase = l31 * 128;
  const int vslotx = l31 & 15;

  f32x16 acc[2] = {};
  float m_r = -1e30f, l_r = 0.0f;

  const int nkb = (65 - tier) >> 1;    // KV blocks of 128 (covers heavy tile)
  u16x8 va, vb, vc, vd;

  // prologue: stage KV block 0 into buf 0 (4 waves cooperate)
  {
#pragma unroll
    for (int c = 0; c < 4; ++c)
      gload_lds16(qkv + (long)(krow0 + c * 8) * QKV_LD + kcol + kOff,
                  &Ks[0][wid * 32 + c * 8][0]);
    const u16* vp = qkv16 + (long)(wid * 32) * QKV_LD + vcol + lane;
#pragma unroll
    for (int j = 0; j < 8; ++j) va[j] = vp[(long)j * QKV_LD];
#pragma unroll
    for (int j = 0; j < 8; ++j) vb[j] = vp[(long)(8 + j) * QKV_LD];
#pragma unroll
    for (int j = 0; j < 8; ++j) vc[j] = vp[(long)(16 + j) * QKV_LD];
#pragma unroll
    for (int j = 0; j < 8; ++j) vd[j] = vp[(long)(24 + j) * QKV_LD];
    *(u16x8*)(&Vt[0][lane][((wid * 4 + 0) ^ (lane & 15)) * 8]) = va;
    *(u16x8*)(&Vt[0][lane][((wid * 4 + 1) ^ (lane & 15)) * 8]) = vb;
    *(u16x8*)(&Vt[0][lane][((wid * 4 + 2) ^ (lane & 15)) * 8]) = vc;
    *(u16x8*)(&Vt[0][lane][((wid * 4 + 3) ^ (lane & 15)) * 8]) = vd;
  }

  for (int kb = 0; kb < nkb; ++kb) {
    const int cur = kb & 1;
    const int kv0 = kb * 128;
    const bool pre = (kb + 1 < nkb);
    __syncthreads();   // staging of block kb visible; prev iter reads done

    // prefetch next KV block: K -> LDS (other buf) async, V -> regs
    if (pre) {
      const long kvn = kv0 + 128;
#pragma unroll
      for (int c = 0; c < 4; ++c)
        gload_lds16(qkv + (kvn + krow0 + c * 8) * QKV_LD + kcol + kOff,
                    &Ks[cur ^ 1][wid * 32 + c * 8][0]);
      const u16* vp = qkv16 + (kvn + wid * 32) * QKV_LD + vcol + lane;
#pragma unroll
      for (int j = 0; j < 8; ++j) va[j] = vp[(long)j * QKV_LD];
#pragma unroll
      for (int j = 0; j < 8; ++j) vb[j] = vp[(long)(8 + j) * QKV_LD];
#pragma unroll
      for (int j = 0; j < 8; ++j) vc[j] = vp[(long)(16 + j) * QKV_LD];
#pragma unroll
      for (int j = 0; j < 8; ++j) vd[j] = vp[(long)(24 + j) * QKV_LD];
    }

    const bf16* KsC = &Ks[cur][0][0];
    const bf16* VtC = &Vt[cur][0][0];

#pragma unroll
    for (int sub = 0; sub < 4; ++sub) {
      const int kvs = kv0 + sub * 32;
      if (kvs > q0w + 31) continue;        // wave-uniform skip

      // S^T = K * Q^T over d=64 (4 mfma of k=16)
      f32x16 c16 = {};
#pragma unroll
      for (int kt = 0; kt < 4; ++kt) {
        bf16x8 kf = *(const bf16x8*)(KsC + sub * 2048 + kro[kt]);
        c16 = mfma32(kf, qf[kt], c16);
      }

      // causal mask (diagonal region only)
      if (kvs + 31 > q0w) {
        const int q = q0w + l31;
        const int kvb = kvs + 4 * hi;
#pragma unroll
        for (int r = 0; r < 16; ++r) {
          int kv = kvb + (r & 3) + 8 * (r >> 2);
          if (kv > q) c16[r] = -1e30f;
        }
      }

      // per-lane online softmax (q = l31); pair (l, l^32) holds the 32 kv
      float t0 = fmaxf(fmaxf(c16[0], c16[1]), fmaxf(c16[2], c16[3]));
      float t1 = fmaxf(fmaxf(c16[4], c16[5]), fmaxf(c16[6], c16[7]));
      float t2 = fmaxf(fmaxf(c16[8], c16[9]), fmaxf(c16[10], c16[11]));
      float t3 = fmaxf(fmaxf(c16[12], c16[13]), fmaxf(c16[14], c16[15]));
      float pmax = fmaxf(fmaxf(t0, t1), fmaxf(t2, t3));
      pmax = fmaxf(pmax, __shfl_xor(pmax, 32, 64));

      if (!__all(pmax <= m_r + 8.0f)) {    // defer-max (T13)
        float mn = fmaxf(m_r, pmax);
        float al = __expf(m_r - mn);
        m_r = mn;
        l_r *= al;
#pragma unroll
        for (int dt = 0; dt < 2; ++dt)
#pragma unroll
          for (int r = 0; r < 16; ++r) acc[dt][r] *= al;
      }

      float p[16];
#pragma unroll
      for (int r = 0; r < 16; ++r) p[r] = __expf(c16[r] - m_r);
      float rs = ((p[0] + p[1]) + (p[2] + p[3])) + ((p[4] + p[5]) + (p[6] + p[7])) +
                 (((p[8] + p[9]) + (p[10] + p[11])) + ((p[12] + p[13]) + (p[14] + p[15])));
      rs += __shfl_xor(rs, 32, 64);
      l_r += rs;

      // P^T -> B-fragments: pack pairs to bf16x2 words, exchange across l^32
      // (v4/v5-proven shfl_xor construction)
      union BP { u32 u[4]; bf16x8 v; } f0, f1;
      {
        u32 x01 = pkbf(p[0], p[1]), x23 = pkbf(p[2], p[3]);
        u32 x45 = pkbf(p[4], p[5]), x67 = pkbf(p[6], p[7]);
        u32 s01 = __shfl_xor(x01, 32, 64), s23 = __shfl_xor(x23, 32, 64);
        u32 s45 = __shfl_xor(x45, 32, 64), s67 = __shfl_xor(x67, 32, 64);
        f0.u[0] = hi ? s45 : x01;
        f0.u[1] = hi ? s67 : x23;
        f0.u[2] = hi ? x45 : s01;
        f0.u[3] = hi ? x67 : s23;
      }
      {
        u32 x01 = pkbf(p[8], p[9]), x23 = pkbf(p[10], p[11]);
        u32 x45 = pkbf(p[12], p[13]), x67 = pkbf(p[14], p[15]);
        u32 s01 = __shfl_xor(x01, 32, 64), s23 = __shfl_xor(x23, 32, 64);
        u32 s45 = __shfl_xor(x45, 32, 64), s67 = __shfl_xor(x67, 32, 64);
        f1.u[0] = hi ? s45 : x01;
        f1.u[1] = hi ? s67 : x23;
        f1.u[2] = hi ? x45 : s01;
        f1.u[3] = hi ? x67 : s23;
      }

      // O^T += V^T * P^T
#pragma unroll
      for (int dt = 0; dt < 2; ++dt) {
        const bf16* vrow = VtC + dt * 4096 + vbase;
        bf16x8 vf0 = *(const bf16x8*)(vrow + (((sub * 4 + hi) ^ vslotx) * 8));
        acc[dt] = mfma32(vf0, f0.v, acc[dt]);
        bf16x8 vf1 = *(const bf16x8*)(vrow + (((sub * 4 + 2 + hi) ^ vslotx) * 8));
        acc[dt] = mfma32(vf1, f1.v, acc[dt]);
      }
    }

    // write staged V regs into the other buffer
    if (pre) {
      const int nb = cur ^ 1;
      *(u16x8*)(&Vt[nb][lane][((wid * 4 + 0) ^ (lane & 15)) * 8]) = va;
      *(u16x8*)(&Vt[nb][lane][((wid * 4 + 1) ^ (lane & 15)) * 8]) = vb;
      *(u16x8*)(&Vt[nb][lane][((wid * 4 + 2) ^ (lane & 15)) * 8]) = vc;
      *(u16x8*)(&Vt[nb][lane][((wid * 4 + 3) ^ (lane & 15)) * 8]) = vd;
    }
  }

  __syncthreads();   // all waves done with Ks/Vt; LDS reused for epilogue

  // epilogue: O^T regs -> per-wave LDS [32 q][68 d] -> coalesced ctx store
  bf16* scr = smem + wid * 2176;
  const float inv = 1.0f / l_r;
#pragma unroll
  for (int dt = 0; dt < 2; ++dt)
#pragma unroll
    for (int g2 = 0; g2 < 4; ++g2) {
      union { u16 hh[4]; unsigned long long q8; } pk4;
#pragma unroll
      for (int j = 0; j < 4; ++j) pk4.hh[j] = f2b(acc[dt][g2 * 4 + j] * inv);
      *(unsigned long long*)(scr + l31 * 68 + dt * 32 + g2 * 8 + 4 * hi) = pk4.q8;
    }
  __syncthreads();   // writes ordered & visible before cross-lane reads

  const int qe = lane >> 1, he = lane & 1;
  u16* cp = (u16*)ctx + (long)(q0w + qe) * DMODEL + h * HD + he * 32;
#pragma unroll
  for (int j = 0; j < 4; ++j) {
    u16x8 v = *(const u16x8*)(scr + qe * 68 + he * 32 + j * 8);
    *(u16x8*)(cp + j * 8) = v;
  }
}

extern "C" void kernel_launch(void* const* d_in, const int* in_sizes, int n_in,
                              void* d_out, int out_size, void* d_ws, size_t ws_size,
                              hipStream_t stream) {
  (void)in_sizes; (void)n_in; (void)out_size; (void)ws_size;
  const float* x  = (const float*)d_in[0];
  const float* Wq = (const float*)d_in[1];
  const float* Wk = (const float*)d_in[2];
  const float* Wv = (const float*)d_in[3];
  const float* Wo = (const float*)d_in[4];
  const float* bo = (const float*)d_in[5];
  float* out = (float*)d_out;

  char* ws = (char*)d_ws;
  bf16* xb   = (bf16*)(ws);                   //  8 MB: x in bf16 [4096,1024]
  bf16* wqkv = (bf16*)(ws + 8388608);         //  6 MB: packed Wq;Wk;Wv [3072,1024]
  bf16* wob  = (bf16*)(ws + 14680064);        //  2 MB: Wo [1024,1024]
  bf16* qkvb = (bf16*)(ws + 16777216);        // 24 MB: QKV [4096,3072]
  bf16* ctxb = (bf16*)(ws + 41943040);        //  8 MB: ctx [4096,1024]

  cvt_kernel<<<dim3(4096), dim3(256), 0, stream>>>(x, xb, 4194304);
  cvt_kernel<<<dim3(1024), dim3(256), 0, stream>>>(Wq, wqkv, 1048576);
  cvt_kernel<<<dim3(1024), dim3(256), 0, stream>>>(Wk, wqkv + 1048576, 1048576);
  cvt_kernel<<<dim3(1024), dim3(256), 0, stream>>>(Wv, wqkv + 2097152, 1048576);
  cvt_kernel<<<dim3(1024), dim3(256), 0, stream>>>(Wo, wob, 1048576);

  gemm_bt<1><<<dim3(24, 32), dim3(256), 0, stream>>>(xb, wqkv, (void*)qkvb, nullptr,
                                                     4096, 3072, 1024);
  rope_kernel<<<dim3(16384), dim3(256), 0, stream>>>(qkvb);
  attn_kernel<<<dim3(512), dim3(256), 0, stream>>>(qkvb, ctxb);
  gemm_bt<0><<<dim3(8, 32), dim3(256), 0, stream>>>(ctxb, wob, (void*)out, bo,
                                                    4096, 1024, 1024);
}

// Round 9
// 203.551 us; speedup vs baseline: 1.0637x; 1.0637x over previous
//
#include <hip/hip_runtime.h>
#include <hip/hip_bf16.h>

typedef __hip_bfloat16 bf16;
typedef unsigned short u16;
typedef unsigned int u32;
typedef float f32x4 __attribute__((ext_vector_type(4)));
typedef float f32x16 __attribute__((ext_vector_type(16)));
typedef __bf16 bf16x8 __attribute__((ext_vector_type(8)));
typedef u16 u16x8 __attribute__((ext_vector_type(8)));

#define DMODEL 1024
#define NH 16
#define HD 64
#define QKV_LD 3072

typedef __attribute__((address_space(1))) const void* as1_cvp;
typedef __attribute__((address_space(3))) void* as3_vp;

__device__ __forceinline__ void gload_lds16(const void* g, void* l) {
  __builtin_amdgcn_global_load_lds((as1_cvp)g, (as3_vp)l, 16, 0, 0);
}

__device__ __forceinline__ f32x4 mfma16(bf16x8 a, bf16x8 b, f32x4 c) {
  return __builtin_amdgcn_mfma_f32_16x16x32_bf16(a, b, c, 0, 0, 0);
}
__device__ __forceinline__ f32x16 mfma32(bf16x8 a, bf16x8 b, f32x16 c) {
  return __builtin_amdgcn_mfma_f32_32x32x16_bf16(a, b, c, 0, 0, 0);
}

__device__ __forceinline__ u16 f2b(float f) {
  union { bf16 b; u16 s; } u; u.b = __float2bfloat16(f); return u.s;
}
__device__ __forceinline__ u32 pkbf(float a, float b) {
  union { __hip_bfloat162 h; u32 u; } cv;
  cv.h = __float22bfloat162_rn(make_float2(a, b));
  return cv.u;
}

// ---------------- fp32 -> bf16 conversion, 4 elems/thread ----------------
__global__ __launch_bounds__(256) void cvt_kernel(const float* __restrict__ src,
                                                  bf16* __restrict__ dst, int n) {
  int i = (blockIdx.x * 256 + threadIdx.x) * 4;
  if (i >= n) return;
  float4 v = *(const float4*)(src + i);
  union { ushort4 u; bf16 h[4]; } o;
  o.h[0] = __float2bfloat16(v.x);
  o.h[1] = __float2bfloat16(v.y);
  o.h[2] = __float2bfloat16(v.z);
  o.h[3] = __float2bfloat16(v.w);
  *(ushort4*)(dst + i) = o.u;
}

// ---------------- RoPE on Q and K regions of QKV, in place ----------------
__global__ __launch_bounds__(256) void rope_kernel(bf16* __restrict__ qkv) {
  int idx = blockIdx.x * 256 + threadIdx.x;
  int p = idx & 511;
  int s = (idx >> 9) & 4095;
  int region = idx >> 21;
  int i = p & 31;
  int h = p >> 5;
  long base = (long)s * QKV_LD + region * DMODEL + h * HD + 2 * i;
  float x1 = __bfloat162float(qkv[base]);
  float x2 = __bfloat162float(qkv[base + 1]);
  float invf = powf(10000.0f, -(float)(2 * i) / 64.0f);
  float ang = (float)s * invf;
  float sn, cs;
  sincosf(ang, &sn, &cs);
  float scale = (region == 0) ? 0.125f : 1.0f;
  float r1 = (x1 * cs - x2 * sn) * scale;
  float r2 = (x1 * sn + x2 * cs) * scale;
  qkv[base]     = __float2bfloat16(r1);
  qkv[base + 1] = __float2bfloat16(r2);
}

// ---------------- NT GEMM (unchanged) ----------------
template <int OUT_BF16>
__global__ __launch_bounds__(256) void gemm_bt(const bf16* __restrict__ A,
                                               const bf16* __restrict__ B,
                                               void* __restrict__ Cout,
                                               const float* __restrict__ bias,
                                               int M, int N, int K) {
  __shared__ __align__(16) bf16 As[128 * 32];
  __shared__ __align__(16) bf16 Bs[128 * 32];
  const int tid = threadIdx.x;
  const int lane = tid & 63;
  const int wid = tid >> 6;
  const int brow = blockIdx.y * 128;
  const int bcol = blockIdx.x * 128;
  const int wr = wid >> 1, wc = wid & 1;

  f32x4 acc[4][4] = {};

  const int srow = lane >> 2;
  const int scol = (lane & 3) * 8;
  const bf16* Ag = A + (long)(brow + wid * 32 + srow) * K + scol;
  const bf16* Bg = B + (long)(bcol + wid * 32 + srow) * K + scol;
  bf16* AsW = As + wid * 32 * 32;
  bf16* BsW = Bs + wid * 32 * 32;
  const int kof = (lane >> 4) * 8;
  const int r16 = lane & 15;

  for (int k0 = 0; k0 < K; k0 += 32) {
    __syncthreads();
    gload_lds16(Ag + k0, AsW);
    gload_lds16(Ag + k0 + (long)16 * K, AsW + 16 * 32);
    gload_lds16(Bg + k0, BsW);
    gload_lds16(Bg + k0 + (long)16 * K, BsW + 16 * 32);
    __syncthreads();
    bf16x8 af[4], bfr[4];
#pragma unroll
    for (int m = 0; m < 4; ++m)
      af[m] = *(const bf16x8*)(As + (wr * 64 + m * 16 + r16) * 32 + kof);
#pragma unroll
    for (int n = 0; n < 4; ++n)
      bfr[n] = *(const bf16x8*)(Bs + (wc * 64 + n * 16 + r16) * 32 + kof);
#pragma unroll
    for (int m = 0; m < 4; ++m)
#pragma unroll
      for (int n = 0; n < 4; ++n)
        acc[m][n] = mfma16(af[m], bfr[n], acc[m][n]);
  }

  const int r0 = (lane >> 4) * 4;
#pragma unroll
  for (int m = 0; m < 4; ++m) {
#pragma unroll
    for (int n = 0; n < 4; ++n) {
      int row = brow + wr * 64 + m * 16 + r0;
      int col = bcol + wc * 64 + n * 16 + r16;
#pragma unroll
      for (int r = 0; r < 4; ++r) {
        if (OUT_BF16) {
          ((bf16*)Cout)[(long)(row + r) * N + col] = __float2bfloat16(acc[m][n][r]);
        } else {
          ((float*)Cout)[(long)(row + r) * N + col] = acc[m][n][r] + bias[col];
        }
      }
    }
  }
}

// ---------------- causal flash attention (v8: sigma-permuted K rows) --------
// v7 + three changes:
// (1) K rows staged sigma-permuted: sigma(i) = (i&3) + 8*((i>>2)&1) +
//     4*((i>>3)&1) + 16*(i>>4). With this, the 32x32 C-layout registers of
//     S^T hold kv = kvs + (r&3) + 4*((r>>2)&1) + 8*hi + 16*((r>>3)&1), and
//     the PV B-fragments are straight pairwise packs of p[] IN ORDER —
//     the 8 ds_bpermute + 8 selects per sub-block are GONE. Mask uses the
//     closed form; V/Q/epilogue unchanged; max/sum keep 1 shfl each.
// (2) balanced tier pairing: block i pairs with i+256 (same CU under
//     round-robin dispatch) so summed iteration counts are ~constant.
// (3) s_setprio(1) around MFMA clusters (T5); max3-shaped max tree (T17).
__global__ __launch_bounds__(256, 2) void attn_kernel(const bf16* __restrict__ qkv,
                                                      bf16* __restrict__ ctx) {
  __shared__ __align__(16) bf16 smem[32768];   // 64 KB
  bf16 (*Ks)[128][64] = (bf16(*)[128][64])(smem);           // 2 bufs, [kv][d]
  bf16 (*Vt)[64][128] = (bf16(*)[64][128])(smem + 16384);   // 2 bufs, [d][kv]

  const int tid = threadIdx.x;
  const int lane = tid & 63;
  const int wid = tid >> 6;            // 0..3
  const int hi = lane >> 5;
  const int l31 = lane & 31;
  const int bq = blockIdx.x >> 4;      // 0..31
  const int tier = (blockIdx.x < 256) ? bq : (47 - bq);   // balanced pairing
  const int h = blockIdx.x & 15;
  const int grp = wid >> 1;
  const int wslot = wid & 1;
  const int hv = (tier >> 4) & 1;      // which group is heavy
  const int qblk = (grp == hv) ? (63 - tier) : tier;   // 64-row q tile
  const int q0w = qblk * 64 + wslot * 32;              // wave's q base
  const long kcol = DMODEL + (long)h * HD;
  const long vcol = 2 * DMODEL + (long)h * HD;
  const u16* qkv16 = (const u16*)qkv;

  // Q B-fragments: lane holds Q[q=l31][d = kt*16 + hi*8 .. +8]
  bf16x8 qf[4];
  {
    const bf16* qp = qkv + (long)(q0w + l31) * QKV_LD + h * HD + hi * 8;
#pragma unroll
    for (int kt = 0; kt < 4; ++kt) qf[kt] = *(const bf16x8*)(qp + kt * 16);
  }

  const int kOff = ((lane & 7) ^ (lane >> 3)) * 8;   // pre-swizzled K src col
  const int lr = lane >> 3;                          // dest row within 8-chunk
  const int srowp = (lr & 3) + 8 * (lr >> 2);        // sigma base for this lane
  // per-c sigma offsets: c=0,1,2,3 -> 0,4,16,20 (compile-time below)

  // hoisted swizzled LDS element offsets (sub/cur-invariant parts)
  int kro[4];
#pragma unroll
  for (int kt = 0; kt < 4; ++kt)
    kro[kt] = l31 * 64 + ((((kt << 1) | hi) ^ (l31 & 7)) * 8);
  const int vbase = l31 * 128;
  const int vslotx = l31 & 15;

  f32x16 acc[2] = {};
  float m_r = -1e30f, l_r = 0.0f;

  const int nkb = (65 - tier) >> 1;    // KV blocks of 128 (covers heavy tile)
  u16x8 va, vb, vc, vd;

  // prologue: stage KV block 0 into buf 0 (wave wid stages sub wid, sigma rows)
  {
#pragma unroll
    for (int c = 0; c < 4; ++c)
      gload_lds16(qkv + (long)(wid * 32 + srowp + 4 * (c & 1) + 16 * (c >> 1)) * QKV_LD + kcol + kOff,
                  &Ks[0][wid * 32 + c * 8][0]);
    const u16* vp = qkv16 + (long)(wid * 32) * QKV_LD + vcol + lane;
#pragma unroll
    for (int j = 0; j < 8; ++j) va[j] = vp[(long)j * QKV_LD];
#pragma unroll
    for (int j = 0; j < 8; ++j) vb[j] = vp[(long)(8 + j) * QKV_LD];
#pragma unroll
    for (int j = 0; j < 8; ++j) vc[j] = vp[(long)(16 + j) * QKV_LD];
#pragma unroll
    for (int j = 0; j < 8; ++j) vd[j] = vp[(long)(24 + j) * QKV_LD];
    *(u16x8*)(&Vt[0][lane][((wid * 4 + 0) ^ (lane & 15)) * 8]) = va;
    *(u16x8*)(&Vt[0][lane][((wid * 4 + 1) ^ (lane & 15)) * 8]) = vb;
    *(u16x8*)(&Vt[0][lane][((wid * 4 + 2) ^ (lane & 15)) * 8]) = vc;
    *(u16x8*)(&Vt[0][lane][((wid * 4 + 3) ^ (lane & 15)) * 8]) = vd;
  }

  for (int kb = 0; kb < nkb; ++kb) {
    const int cur = kb & 1;
    const int kv0 = kb * 128;
    const bool pre = (kb + 1 < nkb);
    __syncthreads();   // staging of block kb visible; prev iter reads done

    // prefetch next KV block: K -> LDS (other buf, sigma rows), V -> regs
    if (pre) {
      const long kvn = kv0 + 128;
#pragma unroll
      for (int c = 0; c < 4; ++c)
        gload_lds16(qkv + (kvn + wid * 32 + srowp + 4 * (c & 1) + 16 * (c >> 1)) * QKV_LD + kcol + kOff,
                    &Ks[cur ^ 1][wid * 32 + c * 8][0]);
      const u16* vp = qkv16 + (kvn + wid * 32) * QKV_LD + vcol + lane;
#pragma unroll
      for (int j = 0; j < 8; ++j) va[j] = vp[(long)j * QKV_LD];
#pragma unroll
      for (int j = 0; j < 8; ++j) vb[j] = vp[(long)(8 + j) * QKV_LD];
#pragma unroll
      for (int j = 0; j < 8; ++j) vc[j] = vp[(long)(16 + j) * QKV_LD];
#pragma unroll
      for (int j = 0; j < 8; ++j) vd[j] = vp[(long)(24 + j) * QKV_LD];
    }

    const bf16* KsC = &Ks[cur][0][0];
    const bf16* VtC = &Vt[cur][0][0];

#pragma unroll
    for (int sub = 0; sub < 4; ++sub) {
      const int kvs = kv0 + sub * 32;
      if (kvs > q0w + 31) continue;        // wave-uniform skip

      // S^T = K * Q^T over d=64 (4 mfma of k=16)
      f32x16 c16 = {};
      __builtin_amdgcn_s_setprio(1);
#pragma unroll
      for (int kt = 0; kt < 4; ++kt) {
        bf16x8 kf = *(const bf16x8*)(KsC + sub * 2048 + kro[kt]);
        c16 = mfma32(kf, qf[kt], c16);
      }
      __builtin_amdgcn_s_setprio(0);

      // causal mask (diagonal region only); kv of reg r under sigma:
      // kv = kvs + (r&3) + 4*((r>>2)&1) + 8*hi + 16*(r>>3)
      if (kvs + 31 > q0w) {
        const int q = q0w + l31;
        const int kvb = kvs + 8 * hi;
#pragma unroll
        for (int r = 0; r < 16; ++r) {
          int kv = kvb + (r & 3) + 4 * ((r >> 2) & 1) + 16 * (r >> 3);
          if (kv > q) c16[r] = -1e30f;
        }
      }

      // per-lane online softmax (q = l31); pair (l, l^32) holds the 32 kv
      float a0 = fmaxf(fmaxf(c16[0], c16[1]), c16[2]);
      float a1 = fmaxf(fmaxf(c16[3], c16[4]), c16[5]);
      float a2 = fmaxf(fmaxf(c16[6], c16[7]), c16[8]);
      float a3 = fmaxf(fmaxf(c16[9], c16[10]), c16[11]);
      float a4 = fmaxf(fmaxf(c16[12], c16[13]), c16[14]);
      float b0 = fmaxf(fmaxf(a0, a1), a2);
      float b1 = fmaxf(fmaxf(a3, a4), c16[15]);
      float pmax = fmaxf(b0, b1);
      pmax = fmaxf(pmax, __shfl_xor(pmax, 32, 64));

      if (!__all(pmax <= m_r + 8.0f)) {    // defer-max (T13)
        float mn = fmaxf(m_r, pmax);
        float al = __expf(m_r - mn);
        m_r = mn;
        l_r *= al;
#pragma unroll
        for (int dt = 0; dt < 2; ++dt)
#pragma unroll
          for (int r = 0; r < 16; ++r) acc[dt][r] *= al;
      }

      float p[16];
#pragma unroll
      for (int r = 0; r < 16; ++r) p[r] = __expf(c16[r] - m_r);
      float rs = ((p[0] + p[1]) + (p[2] + p[3])) + ((p[4] + p[5]) + (p[6] + p[7])) +
                 (((p[8] + p[9]) + (p[10] + p[11])) + ((p[12] + p[13]) + (p[14] + p[15])));
      rs += __shfl_xor(rs, 32, 64);
      l_r += rs;

      // P^T -> B-fragments: with sigma-permuted rows these are straight
      // in-order pairwise packs. NO cross-lane ops.
      union BP { u32 u[4]; bf16x8 v; } f0, f1;
      f0.u[0] = pkbf(p[0], p[1]);  f0.u[1] = pkbf(p[2], p[3]);
      f0.u[2] = pkbf(p[4], p[5]);  f0.u[3] = pkbf(p[6], p[7]);
      f1.u[0] = pkbf(p[8], p[9]);  f1.u[1] = pkbf(p[10], p[11]);
      f1.u[2] = pkbf(p[12], p[13]); f1.u[3] = pkbf(p[14], p[15]);

      // O^T += V^T * P^T
      __builtin_amdgcn_s_setprio(1);
#pragma unroll
      for (int dt = 0; dt < 2; ++dt) {
        const bf16* vrow = VtC + dt * 4096 + vbase;
        bf16x8 vf0 = *(const bf16x8*)(vrow + (((sub * 4 + hi) ^ vslotx) * 8));
        acc[dt] = mfma32(vf0, f0.v, acc[dt]);
        bf16x8 vf1 = *(const bf16x8*)(vrow + (((sub * 4 + 2 + hi) ^ vslotx) * 8));
        acc[dt] = mfma32(vf1, f1.v, acc[dt]);
      }
      __builtin_amdgcn_s_setprio(0);
    }

    // write staged V regs into the other buffer
    if (pre) {
      const int nb = cur ^ 1;
      *(u16x8*)(&Vt[nb][lane][((wid * 4 + 0) ^ (lane & 15)) * 8]) = va;
      *(u16x8*)(&Vt[nb][lane][((wid * 4 + 1) ^ (lane & 15)) * 8]) = vb;
      *(u16x8*)(&Vt[nb][lane][((wid * 4 + 2) ^ (lane & 15)) * 8]) = vc;
      *(u16x8*)(&Vt[nb][lane][((wid * 4 + 3) ^ (lane & 15)) * 8]) = vd;
    }
  }

  __syncthreads();   // all waves done with Ks/Vt; LDS reused for epilogue

  // epilogue: O^T regs -> per-wave LDS [32 q][68 d] -> coalesced ctx store
  bf16* scr = smem + wid * 2176;
  const float inv = 1.0f / l_r;
#pragma unroll
  for (int dt = 0; dt < 2; ++dt)
#pragma unroll
    for (int g2 = 0; g2 < 4; ++g2) {
      union { u16 hh[4]; unsigned long long q8; } pk4;
#pragma unroll
      for (int j = 0; j < 4; ++j) pk4.hh[j] = f2b(acc[dt][g2 * 4 + j] * inv);
      *(unsigned long long*)(scr + l31 * 68 + dt * 32 + g2 * 8 + 4 * hi) = pk4.q8;
    }
  __syncthreads();   // writes ordered & visible before cross-lane reads

  const int qe = lane >> 1, he = lane & 1;
  u16* cp = (u16*)ctx + (long)(q0w + qe) * DMODEL + h * HD + he * 32;
#pragma unroll
  for (int j = 0; j < 4; ++j) {
    u16x8 v = *(const u16x8*)(scr + qe * 68 + he * 32 + j * 8);
    *(u16x8*)(cp + j * 8) = v;
  }
}

extern "C" void kernel_launch(void* const* d_in, const int* in_sizes, int n_in,
                              void* d_out, int out_size, void* d_ws, size_t ws_size,
                              hipStream_t stream) {
  (void)in_sizes; (void)n_in; (void)out_size; (void)ws_size;
  const float* x  = (const float*)d_in[0];
  const float* Wq = (const float*)d_in[1];
  const float* Wk = (const float*)d_in[2];
  const float* Wv = (const float*)d_in[3];
  const float* Wo = (const float*)d_in[4];
  const float* bo = (const float*)d_in[5];
  float* out = (float*)d_out;

  char* ws = (char*)d_ws;
  bf16* xb   = (bf16*)(ws);                   //  8 MB: x in bf16 [4096,1024]
  bf16* wqkv = (bf16*)(ws + 8388608);         //  6 MB: packed Wq;Wk;Wv [3072,1024]
  bf16* wob  = (bf16*)(ws + 14680064);        //  2 MB: Wo [1024,1024]
  bf16* qkvb = (bf16*)(ws + 16777216);        // 24 MB: QKV [4096,3072]
  bf16* ctxb = (bf16*)(ws + 41943040);        //  8 MB: ctx [4096,1024]

  cvt_kernel<<<dim3(4096), dim3(256), 0, stream>>>(x, xb, 4194304);
  cvt_kernel<<<dim3(1024), dim3(256), 0, stream>>>(Wq, wqkv, 1048576);
  cvt_kernel<<<dim3(1024), dim3(256), 0, stream>>>(Wk, wqkv + 1048576, 1048576);
  cvt_kernel<<<dim3(1024), dim3(256), 0, stream>>>(Wv, wqkv + 2097152, 1048576);
  cvt_kernel<<<dim3(1024), dim3(256), 0, stream>>>(Wo, wob, 1048576);

  gemm_bt<1><<<dim3(24, 32), dim3(256), 0, stream>>>(xb, wqkv, (void*)qkvb, nullptr,
                                                     4096, 3072, 1024);
  rope_kernel<<<dim3(16384), dim3(256), 0, stream>>>(qkvb);
  attn_kernel<<<dim3(512), dim3(256), 0, stream>>>(qkvb, ctxb);
  gemm_bt<0><<<dim3(8, 32), dim3(256), 0, stream>>>(ctxb, wob, (void*)out, bo,
                                                    4096, 1024, 1024);
}